// Round 2
// baseline (298.994 us; speedup 1.0000x reference)
//
#include <hip/hip_runtime.h>
#include <math.h>

#define NORB 13

// block id per orbital index for L_LIST=[0,0,1,1,2] -> sizes 1,1,3,3,5
__device__ __forceinline__ int blk_of(int p) {
    return p < 1 ? 0 : (p < 2 ? 1 : (p < 5 ? 2 : (p < 8 ? 3 : 4)));
}
__device__ __forceinline__ float ffac(int p, int q) {
    int bp = blk_of(p), bq = blk_of(q);
    return bp < bq ? 1.0f : (bp == bq ? 0.5f : 0.0f);
}

// ---- zero exactly n floats of the output (poisoned 0xAA each timed call) ----
__global__ void k_zero(float* __restrict__ out, size_t n) {
    size_t i = (size_t)blockIdx.x * blockDim.x + threadIdx.x;
    size_t stride = (size_t)gridDim.x * blockDim.x;
    float4* o4 = (float4*)out;
    size_t n4 = n >> 2;
    for (size_t j = i; j < n4; j += stride)
        o4[j] = make_float4(0.f, 0.f, 0.f, 0.f);
    for (size_t j = (n4 << 2) + i; j < n; j += stride)  // tail
        out[j] = 0.f;
}

// ---- onsite diagonal blocks: v = ons*F + (ons*F)^T (purely real) ------------
__global__ void k_onsite(const float* __restrict__ onsite, float* __restrict__ out,
                         int K, int ld, int es /*1=real,2=cplx*/, size_t limit) {
    int n = blockIdx.x;
    int t = threadIdx.x;
    if (t >= NORB * NORB) return;
    int p = t / NORB, q = t - p * NORB;
    float v = onsite[(size_t)n * NORB * NORB + p * NORB + q] * ffac(p, q)
            + onsite[(size_t)n * NORB * NORB + q * NORB + p] * ffac(q, p);
    size_t row = (size_t)n * NORB + p;
    size_t col = (size_t)n * NORB + q;
    for (int k = 0; k < K; ++k) {
        size_t idx = (((size_t)k * ld + row) * ld + col) * (size_t)es;
        if (idx < limit) out[idx] = v;  // imag (if any) stays 0 from k_zero
    }
}

// ---- edge scatter: phase*hopF at (ie,je), conj(phase)*hopF at (je,ie)^T -----
__global__ void k_edge(const float* __restrict__ hopping,
                       const float* __restrict__ kpoints,
                       const float* __restrict__ cell_shift,
                       const int* __restrict__ edge_index,
                       float* __restrict__ out,
                       int E, int K, int ld, int es, size_t limit) {
    __shared__ float skp[256];
    int e = blockIdx.x;
    int t = threadIdx.x;
    if (t < 3 * K && t < 256) skp[t] = kpoints[t];
    __syncthreads();
    if (t >= NORB * NORB) return;
    int p = t / NORB, q = t - p * NORB;

    float h = hopping[(size_t)e * NORB * NORB + t] * ffac(p, q);
    int ie = edge_index[e];
    int je = edge_index[E + e];
    float Rx = cell_shift[3 * e + 0];
    float Ry = cell_shift[3 * e + 1];
    float Rz = cell_shift[3 * e + 2];

    int r1 = ie * NORB + p, c1 = je * NORB + q;  // forward block element
    int r2 = je * NORB + q, c2 = ie * NORB + p;  // hermitian counterpart

    for (int k = 0; k < K; ++k) {
        float d = skp[3 * k] * Rx + skp[3 * k + 1] * Ry + skp[3 * k + 2] * Rz;
        float s, c;
        sincosf(-6.2831853071795864f * d, &s, &c);  // exp(-i*2*pi*d) = c + i*s
        float re = c * h, im = s * h;
        size_t b1 = (((size_t)k * ld + r1) * ld + c1) * (size_t)es;
        size_t b2 = (((size_t)k * ld + r2) * ld + c2) * (size_t)es;
        if (b1 < limit) atomicAdd(out + b1, re);
        if (b2 < limit) atomicAdd(out + b2, re);   // Re(conj(phase)*h) == re
        if (es == 2) {
            if (b1 + 1 < limit) atomicAdd(out + b1 + 1, im);
            if (b2 + 1 < limit) atomicAdd(out + b2 + 1, -im);
        }
    }
}

extern "C" void kernel_launch(void* const* d_in, const int* in_sizes, int n_in,
                              void* d_out, int out_size, void* d_ws, size_t ws_size,
                              hipStream_t stream) {
    const float* hopping    = (const float*)d_in[0];
    const float* onsite     = (const float*)d_in[1];
    const float* kpoints    = (const float*)d_in[2];
    const float* cell_shift = (const float*)d_in[3];
    const int*   edge_index = (const int*)d_in[4];
    float* out = (float*)d_out;

    int E = in_sizes[0] / (NORB * NORB);   // 2048
    int N = in_sizes[1] / (NORB * NORB);   // 128
    int K = in_sizes[2] / 3;               // 16
    int ld = N * NORB;                     // 1664

    // Layout detection: complex64 viewed as float pairs -> out_size == K*ld*ld*2.
    // If the harness cast the reference to real float32 -> out_size == K*ld*ld.
    size_t full = (size_t)K * ld * ld * 2;
    int es = ((size_t)out_size >= full) ? 2 : 1;
    size_t limit = (size_t)out_size;

    // 1) zero the whole buffer (exactly out_size floats -> cannot overflow)
    k_zero<<<8192, 256, 0, stream>>>(out, limit);

    // 2) onsite diagonal blocks (plain stores, stream-ordered after zero)
    k_onsite<<<N, 192, 0, stream>>>(onsite, out, K, ld, es, limit);

    // 3) edge scatter with analytic hermitization (atomics accumulate
    //    duplicate (i,j) pairs and self-edge overlaps correctly)
    k_edge<<<E, 192, 0, stream>>>(hopping, kpoints, cell_shift, edge_index, out,
                                  E, K, ld, es, limit);
}

// Round 3
// 275.914 us; speedup vs baseline: 1.0836x; 1.0836x over previous
//
#include <hip/hip_runtime.h>
#include <math.h>

#define NORB 13
#define NORB2 (NORB * NORB)

// block id per orbital index for L_LIST=[0,0,1,1,2] -> sizes 1,1,3,3,5
__device__ __forceinline__ int blk_of(int p) {
    return p < 1 ? 0 : (p < 2 ? 1 : (p < 5 ? 2 : (p < 8 ? 3 : 4)));
}
__device__ __forceinline__ float ffac(int p, int q) {
    int bp = blk_of(p), bq = blk_of(q);
    return bp < bq ? 1.0f : (bp == bq ? 0.5f : 0.0f);
}

// ---------------- CSR build over destination blocks --------------------------
__global__ void k_ws_zero(int* __restrict__ cnt, int nbins) {
    int i = blockIdx.x * blockDim.x + threadIdx.x;
    if (i < nbins) cnt[i] = 0;
}

__global__ void k_count(const int* __restrict__ edge_index, int* __restrict__ cnt,
                        int E, int N) {
    int e = blockIdx.x * blockDim.x + threadIdx.x;
    if (e >= E) return;
    int ie = edge_index[e], je = edge_index[E + e];
    atomicAdd(cnt + ie * N + je, 1);   // forward contribution to block (ie,je)
    atomicAdd(cnt + je * N + ie, 1);   // hermitian contribution to block (je,ie)
}

// single-workgroup exclusive scan over nbins (nbins = N*N, multiple of 256)
__global__ void k_scan(const int* __restrict__ cnt, int* __restrict__ rowptr,
                       int* __restrict__ cursor, int nbins) {
    __shared__ int part[257];
    int tid = threadIdx.x;
    int per = nbins / 256;
    int base = tid * per;
    int s = 0;
    for (int i = 0; i < per; ++i) s += cnt[base + i];
    part[tid + 1] = s;
    __syncthreads();
    if (tid == 0) {
        part[0] = 0;
        for (int i = 1; i <= 256; ++i) part[i] += part[i - 1];
    }
    __syncthreads();
    int run = part[tid];
    for (int i = 0; i < per; ++i) {
        rowptr[base + i] = run;
        cursor[base + i] = run;
        run += cnt[base + i];
    }
    if (tid == 255) rowptr[nbins] = run;
}

__global__ void k_fill(const int* __restrict__ edge_index, int* __restrict__ cursor,
                       int* __restrict__ entries, int E, int N) {
    int e = blockIdx.x * blockDim.x + threadIdx.x;
    if (e >= E) return;
    int ie = edge_index[e], je = edge_index[E + e];
    int pos = atomicAdd(cursor + ie * N + je, 1);
    entries[pos] = (e << 1);           // forward: phase * hopF
    pos = atomicAdd(cursor + je * N + ie, 1);
    entries[pos] = (e << 1) | 1;       // reverse: conj(phase) * hopF^T
}

// ---------------- dense fused assemble: one wave per (k,a,b) block -----------
// Writes every output element exactly once (plain stores, no atomics, no
// separate zero-fill). Handles both complex-interleaved (es=2) and real (es=1).
__global__ void k_assemble(const float* __restrict__ hopping,
                           const float* __restrict__ onsite,
                           const float* __restrict__ kpoints,
                           const float* __restrict__ cell_shift,
                           const int* __restrict__ rowptr,
                           const int* __restrict__ entries,
                           float* __restrict__ out,
                           int N, int K, int ld, int es, int ntiles) {
    int wave = blockIdx.x * (blockDim.x >> 6) + (threadIdx.x >> 6);
    if (wave >= ntiles) return;
    int lane = threadIdx.x & 63;

    int b = wave % N;
    int a = (wave / N) % N;
    int k = wave / (N * N);

    // per-lane element slots t = lane, lane+64, lane+128 (t < 169)
    int   pp[3], qq[3], offf[3], offr[3];
    float ff[3], fr[3];
    bool  valid[3];
#pragma unroll
    for (int j = 0; j < 3; ++j) {
        int t = lane + 64 * j;
        valid[j] = (t < NORB2);
        int tt = valid[j] ? t : 0;
        int p = tt / NORB, q = tt - p * NORB;
        pp[j] = p; qq[j] = q;
        offf[j] = p * NORB + q;
        offr[j] = q * NORB + p;
        ff[j] = valid[j] ? ffac(p, q) : 0.f;
        fr[j] = valid[j] ? ffac(q, p) : 0.f;
    }

    float accre[3] = {0.f, 0.f, 0.f};
    float accim[3] = {0.f, 0.f, 0.f};

    // onsite hermitized term on diagonal blocks: ons*F + (ons*F)^T (real)
    if (a == b) {
        const float* on = onsite + (size_t)a * NORB2;
#pragma unroll
        for (int j = 0; j < 3; ++j)
            accre[j] = on[offf[j]] * ff[j] + on[offr[j]] * fr[j];
    }

    float kx = kpoints[3 * k], ky = kpoints[3 * k + 1], kz = kpoints[3 * k + 2];

    int bin = a * N + b;
    int beg = rowptr[bin], end = rowptr[bin + 1];
    for (int i = beg; i < end; ++i) {
        int ent = entries[i];
        int e = ent >> 1;
        int rev = ent & 1;
        float Rx = cell_shift[3 * e], Ry = cell_shift[3 * e + 1], Rz = cell_shift[3 * e + 2];
        float d = kx * Rx + ky * Ry + kz * Rz;
        float s, c;
        sincosf(6.2831853071795864f * d, &s, &c);  // exp(-i*2*pi*d) = c - i*s
        float ims = rev ? s : -s;                  // conj for reverse direction
        const float* h = hopping + (size_t)e * NORB2;
#pragma unroll
        for (int j = 0; j < 3; ++j) {
            float hv = rev ? h[offr[j]] * fr[j] : h[offf[j]] * ff[j];
            accre[j] += c * hv;
            accim[j] += ims * hv;
        }
    }

    // store the 13x13 block
    if (es == 2) {
        float2* o2 = (float2*)out;
#pragma unroll
        for (int j = 0; j < 3; ++j) {
            if (!valid[j]) continue;
            size_t idx = ((size_t)k * ld + a * NORB + pp[j]) * ld + b * NORB + qq[j];
            o2[idx] = make_float2(accre[j], accim[j]);
        }
    } else {
#pragma unroll
        for (int j = 0; j < 3; ++j) {
            if (!valid[j]) continue;
            size_t idx = ((size_t)k * ld + a * NORB + pp[j]) * ld + b * NORB + qq[j];
            out[idx] = accre[j];
        }
    }
}

extern "C" void kernel_launch(void* const* d_in, const int* in_sizes, int n_in,
                              void* d_out, int out_size, void* d_ws, size_t ws_size,
                              hipStream_t stream) {
    const float* hopping    = (const float*)d_in[0];
    const float* onsite     = (const float*)d_in[1];
    const float* kpoints    = (const float*)d_in[2];
    const float* cell_shift = (const float*)d_in[3];
    const int*   edge_index = (const int*)d_in[4];
    float* out = (float*)d_out;

    int E = in_sizes[0] / NORB2;   // 2048
    int N = in_sizes[1] / NORB2;   // 128
    int K = in_sizes[2] / 3;       // 16
    int ld = N * NORB;             // 1664
    int nbins = N * N;             // 16384

    // complex-interleaved vs real layout detection (constant across calls)
    size_t full = (size_t)K * ld * ld * 2;
    int es = ((size_t)out_size >= full) ? 2 : 1;

    // workspace layout (ints): cnt[nbins], rowptr[nbins+1], cursor[nbins], entries[2E]
    int* cnt     = (int*)d_ws;
    int* rowptr  = cnt + nbins;
    int* cursor  = rowptr + nbins + 1;
    int* entries = cursor + nbins;
    // requires ws_size >= (3*nbins + 1 + 2*E) * 4 bytes  (~229 KB here)

    k_ws_zero<<<(nbins + 255) / 256, 256, 0, stream>>>(cnt, nbins);
    k_count  <<<(E + 255) / 256, 256, 0, stream>>>(edge_index, cnt, E, N);
    k_scan   <<<1, 256, 0, stream>>>(cnt, rowptr, cursor, nbins);
    k_fill   <<<(E + 255) / 256, 256, 0, stream>>>(edge_index, cursor, entries, E, N);

    int ntiles = K * N * N;                     // one wave per (k,a,b) block
    int wgs = (ntiles + 3) / 4;                 // 4 waves (256 threads) per WG
    k_assemble<<<wgs, 256, 0, stream>>>(hopping, onsite, kpoints, cell_shift,
                                        rowptr, entries, out, N, K, ld, es, ntiles);
}